// Round 2
// baseline (208.287 us; speedup 1.0000x reference)
//
#include <hip/hip_runtime.h>
#include <hip/hip_bf16.h>

#define N_NODES 8192
#define N_IN 512
#define N_OUT 512

typedef __bf16 bf16;
typedef __bf16 bf16x4 __attribute__((ext_vector_type(4)));
typedef __bf16 bf16x8 __attribute__((ext_vector_type(8)));
typedef float f32x4 __attribute__((ext_vector_type(4)));

__device__ __forceinline__ void gload16(const void* g, void* l) {
  __builtin_amdgcn_global_load_lds((const __attribute__((address_space(1))) void*)g,
                                   (__attribute__((address_space(3))) void*)l, 16, 0, 0);
}

#define WAITVM(N) asm volatile("s_waitcnt vmcnt(" #N ")" ::: "memory")

// ---- kernel 1: column partial sums of adj + fp32->bf16 convert (one fused pass) ----
__global__ __launch_bounds__(256) void k_colsum_cvt(const float* __restrict__ adj,
                                                    bf16* __restrict__ adjb,
                                                    float* __restrict__ partial) {
  const int tid  = threadIdx.x;
  const int col0 = blockIdx.x * 1024 + tid * 4;
  const int row0 = blockIdx.y * 64;
  float s0 = 0.f, s1 = 0.f, s2 = 0.f, s3 = 0.f;
#pragma unroll 4
  for (int r = 0; r < 64; ++r) {
    const float4 v = *reinterpret_cast<const float4*>(adj + (size_t)(row0 + r) * N_NODES + col0);
    s0 += v.x; s1 += v.y; s2 += v.z; s3 += v.w;
    bf16x4 o = { (bf16)v.x, (bf16)v.y, (bf16)v.z, (bf16)v.w };
    *reinterpret_cast<bf16x4*>(adjb + (size_t)(row0 + r) * N_NODES + col0) = o;
  }
  float4 ps = { s0, s1, s2, s3 };
  *reinterpret_cast<float4*>(partial + (size_t)blockIdx.y * N_NODES + col0) = ps;
}

// ---- kernel 2: d[j] = rsqrt(1 + colsum) ----
__global__ __launch_bounds__(256) void k_dvec(const float* __restrict__ partial,
                                              float* __restrict__ dv) {
  const int j = blockIdx.x * 256 + threadIdx.x;
  float s = 1.0f;  // +1 from the identity (self-loop)
#pragma unroll 8
  for (int p = 0; p < 128; ++p) s += partial[(size_t)p * N_NODES + j];
  dv[j] = rsqrtf(s);
}

// ---- kernel 3: Hst[k][j] = d[j]*H[j][k]  (transpose+scale, bf16; B^T layout for GEMM1) ----
__global__ __launch_bounds__(256) void k_hst(const float* __restrict__ H,
                                             const float* __restrict__ dv,
                                             bf16* __restrict__ Hst) {
  __shared__ float t[64][65];
  const int tid = threadIdx.x;
  const int j0 = blockIdx.x * 64;
  const int k0 = blockIdx.y * 64;
  const int rr = tid >> 4;         // 0..15
  const int cc = (tid & 15) * 4;   // 0..60
#pragma unroll
  for (int p = 0; p < 4; ++p) {
    const int r = p * 16 + rr;
    const float d = dv[j0 + r];
    float4 v = *reinterpret_cast<const float4*>(H + (size_t)(j0 + r) * N_IN + k0 + cc);
    t[r][cc + 0] = v.x * d; t[r][cc + 1] = v.y * d;
    t[r][cc + 2] = v.z * d; t[r][cc + 3] = v.w * d;
  }
  __syncthreads();
#pragma unroll
  for (int p = 0; p < 4; ++p) {
    const int kr = p * 16 + rr;
    bf16x4 o = { (bf16)t[cc + 0][kr], (bf16)t[cc + 1][kr],
                 (bf16)t[cc + 2][kr], (bf16)t[cc + 3][kr] };
    *reinterpret_cast<bf16x4*>(Hst + (size_t)(k0 + kr) * N_NODES + j0 + cc) = o;
  }
}

// ---- kernel 4: W fp32 -> bf16 (already B^T layout: [NOUT][NIN]) ----
__global__ __launch_bounds__(256) void k_wcvt(const float* __restrict__ W, bf16* __restrict__ Wb) {
  const int i = (blockIdx.x * 256 + threadIdx.x) * 4;
  float4 v = *reinterpret_cast<const float4*>(W + i);
  bf16x4 o = { (bf16)v.x, (bf16)v.y, (bf16)v.z, (bf16)v.w };
  *reinterpret_cast<bf16x4*>(Wb + i) = o;
}

// ---- GEMM: C = A[M x KDIM] @ Bt[ncols x KDIM]^T, 128x128 tile, BK=64, 4 waves ----
// Double-buffered (2 x 32 KB LDS -> 2 blocks/CU), depth-1 prefetch, counted vmcnt(8)
// (never 0 in-loop), raw barriers, both-sides XOR-swizzled LDS, split-K.
// EPI=1: out[i][c] = tanh(acc + bias[c])  (f32)
// EPI=2: P[split][i][c] = acc             (f32 partial, no epilogue)
template<int KDIM, int NSPLIT, int EPI>
__global__ __launch_bounds__(256, 2) void k_gemm(
    const bf16* __restrict__ A, const bf16* __restrict__ B,
    const float* __restrict__ bias, float* __restrict__ outf) {
  constexpr int KSEG = KDIM / NSPLIT;
  constexpr int NT = KSEG / 64;
  constexpr int NBLK = 256 * NSPLIT;
  __shared__ __attribute__((aligned(128))) char lds[2 * 32768];

  // XCD-aware swizzle over the full grid (NBLK % 8 == 0 -> bijective), then
  // tile-major/split-minor so the 4 N-blocks of an M-group are XCD-adjacent.
  const int bid = blockIdx.x;
  const int logical = (bid & 7) * (NBLK / 8) + (bid >> 3);
  const int split = logical & (NSPLIT - 1);
  const int tile = logical / NSPLIT;
  const int bm0 = (tile >> 2) * 128;
  const int bn0 = (tile & 3) * 128;

  const int tid = threadIdx.x;
  const int wid = tid >> 6;
  const int lane = tid & 63;
  const int wr = wid & 1, wc = wid >> 1;   // 2x2 waves, each 64x64 output

  // staging: linear LDS dest (global_load_lds), INVERSE-swizzled global source
  const int srow = tid >> 3;                           // 0..31 within a 32-row chunk
  const int scol = ((tid & 7) ^ (srow & 7)) << 3;      // swizzled source col (elements)
  const size_t a_src = (size_t)(bm0 + srow) * KDIM + (size_t)split * KSEG + scol;
  const size_t b_src = (size_t)(bn0 + srow) * KDIM + (size_t)split * KSEG + scol;

  // fragment reads (swizzled): byte = row*128 + ((kk*64 + fk*16) ^ ((row&7)<<4))
  const int frow = lane & 15;
  const int fk = lane >> 4;                 // 0..3
  const int swz = (lane & 7) << 4;          // row&7 == lane&7 for all fragment rows
  const int a_row_byte = (wr * 64 + frow) * 128;
  const int b_row_byte = 16384 + (wc * 64 + frow) * 128;

  f32x4 acc[4][4] = {};

  auto stage = [&](int t) {
    char* lbase = lds + (t & 1) * 32768;
    const bf16* ag = A + a_src + (size_t)t * 64;
    const bf16* bg = B + b_src + (size_t)t * 64;
#pragma unroll
    for (int ch = 0; ch < 4; ++ch) {
      gload16(ag + (size_t)(ch * 32) * KDIM, lbase + ch * 4096 + wid * 1024);
      gload16(bg + (size_t)(ch * 32) * KDIM, lbase + 16384 + ch * 4096 + wid * 1024);
    }
  };

  auto compute = [&](int t) {
    const char* lbase = lds + (t & 1) * 32768;
#pragma unroll
    for (int kk = 0; kk < 2; ++kk) {
      const int colb = (kk * 64 + fk * 16) ^ swz;
      bf16x8 av[4], bv[4];
#pragma unroll
      for (int m = 0; m < 4; ++m)
        av[m] = *reinterpret_cast<const bf16x8*>(lbase + a_row_byte + m * 2048 + colb);
#pragma unroll
      for (int n = 0; n < 4; ++n)
        bv[n] = *reinterpret_cast<const bf16x8*>(lbase + b_row_byte + n * 2048 + colb);
#pragma unroll
      for (int m = 0; m < 4; ++m)
#pragma unroll
        for (int n = 0; n < 4; ++n)
          acc[m][n] = __builtin_amdgcn_mfma_f32_16x16x32_bf16(av[m], bv[n], acc[m][n], 0, 0, 0);
    }
  };

  stage(0);
#pragma unroll 1
  for (int t = 0; t < NT - 1; ++t) {
    stage(t + 1);                      // 8 loads for tile t+1 stay in flight
    WAITVM(8);                         // tile t drained; t+1 still outstanding
    __builtin_amdgcn_s_barrier();
    asm volatile("" ::: "memory");
    compute(t);
    asm volatile("" ::: "memory");
    __builtin_amdgcn_s_barrier();      // buffer (t&1) rewritten at stage(t+2)
  }
  WAITVM(0);
  __builtin_amdgcn_s_barrier();
  compute(NT - 1);

  // epilogue: C/D layout col = lane&15, row = (lane>>4)*4 + j
#pragma unroll
  for (int m = 0; m < 4; ++m) {
#pragma unroll
    for (int j = 0; j < 4; ++j) {
      const int grow = bm0 + wr * 64 + m * 16 + (lane >> 4) * 4 + j;
      if constexpr (EPI == 2) {
        float* prow = outf + (size_t)split * ((size_t)N_NODES * N_IN) + (size_t)grow * N_IN;
#pragma unroll
        for (int n = 0; n < 4; ++n) {
          const int gcol = bn0 + wc * 64 + n * 16 + (lane & 15);
          prow[gcol] = acc[m][n][j];
        }
      } else {
        float* orow = outf + (size_t)grow * N_OUT;
#pragma unroll
        for (int n = 0; n < 4; ++n) {
          const int gcol = bn0 + wc * 64 + n * 16 + (lane & 15);
          float v = acc[m][n][j] + bias[gcol];
          v = fminf(fmaxf(v, -15.f), 15.f);
          const float e = __expf(2.f * v);
          orow[gcol] = (e - 1.f) / (e + 1.f);
        }
      }
    }
  }
}

// ---- split-K reduce + GCN epilogue: Hm = d_i*(P0+P1) + d_i^2*H  (bf16 out) ----
__global__ __launch_bounds__(256) void k_red(const float* __restrict__ P,
                                             const float* __restrict__ H,
                                             const float* __restrict__ dv,
                                             bf16* __restrict__ Hm) {
  const int t = blockIdx.x * 256 + threadIdx.x;
  const int row = t >> 7;
  const int col = (t & 127) << 2;
  const size_t off = (size_t)row * N_IN + col;
  const float d = dv[row];
  const float d2 = d * d;
  const float4 p0 = *reinterpret_cast<const float4*>(P + off);
  const float4 p1 = *reinterpret_cast<const float4*>(P + (size_t)N_NODES * N_IN + off);
  const float4 h  = *reinterpret_cast<const float4*>(H + off);
  bf16x4 o = { (bf16)(d * (p0.x + p1.x) + d2 * h.x),
               (bf16)(d * (p0.y + p1.y) + d2 * h.y),
               (bf16)(d * (p0.z + p1.z) + d2 * h.z),
               (bf16)(d * (p0.w + p1.w) + d2 * h.w) };
  *reinterpret_cast<bf16x4*>(Hm + off) = o;
}

extern "C" void kernel_launch(void* const* d_in, const int* in_sizes, int n_in,
                              void* d_out, int out_size, void* d_ws, size_t ws_size,
                              hipStream_t stream) {
  const float* H   = (const float*)d_in[0];
  const float* adj = (const float*)d_in[1];
  const float* W   = (const float*)d_in[2];
  const float* b   = (const float*)d_in[3];
  float* out = (float*)d_out;
  char* ws = (char*)d_ws;

  bf16*  adjb = (bf16*)(ws);                    // 8192*8192*2 = 134217728
  bf16*  Hst  = (bf16*)(ws + 134217728);        // 512*8192*2  = 8388608
  bf16*  Hm   = (bf16*)(ws + 142606336);        // 8192*512*2  = 8388608
  bf16*  Wb   = (bf16*)(ws + 150994944);        // 512*512*2   = 524288
  float* part = (float*)(ws + 151519232);       // 128*8192*4  = 4194304
  float* dv   = (float*)(ws + 155713536);       // 8192*4      = 32768
  float* P    = (float*)(ws + 155746304);       // 2*8192*512*4 = 33554432

  k_colsum_cvt<<<dim3(8, 128), 256, 0, stream>>>(adj, adjb, part);
  k_dvec<<<32, 256, 0, stream>>>(part, dv);
  k_hst<<<dim3(128, 8), 256, 0, stream>>>(H, dv, Hst);
  k_wcvt<<<256, 256, 0, stream>>>(W, Wb);
  // P[s] = adjb[:, s-half] @ Hst[s-half]^T   (split-K=2, f32 partials)
  k_gemm<8192, 2, 2><<<512, 256, 0, stream>>>(adjb, Hst, nullptr, P);
  // Hm = d_i*(P0+P1) + d_i^2*H   (bf16)
  k_red<<<4096, 256, 0, stream>>>(P, H, dv, Hm);
  // out = tanh(Hm @ W^T + b)     (f32)
  k_gemm<512, 1, 1><<<256, 256, 0, stream>>>(Hm, Wb, b, out);
}

// Round 3
// 199.234 us; speedup vs baseline: 1.0454x; 1.0454x over previous
//
#include <hip/hip_runtime.h>
#include <hip/hip_bf16.h>

#define N_NODES 8192
#define N_IN 512
#define N_OUT 512

typedef __bf16 bf16;
typedef __bf16 bf16x4 __attribute__((ext_vector_type(4)));
typedef __bf16 bf16x8 __attribute__((ext_vector_type(8)));
typedef float f32x4 __attribute__((ext_vector_type(4)));

__device__ __forceinline__ void gload16(const void* g, void* l) {
  __builtin_amdgcn_global_load_lds((const __attribute__((address_space(1))) void*)g,
                                   (__attribute__((address_space(3))) void*)l, 16, 0, 0);
}

#define WAITVM(N) asm volatile("s_waitcnt vmcnt(" #N ")" ::: "memory")

// ---- kernel 1: column partial sums of adj + fp32->bf16 convert (one fused pass) ----
__global__ __launch_bounds__(256) void k_colsum_cvt(const float* __restrict__ adj,
                                                    bf16* __restrict__ adjb,
                                                    float* __restrict__ partial) {
  const int tid  = threadIdx.x;
  const int col0 = blockIdx.x * 1024 + tid * 4;
  const int row0 = blockIdx.y * 64;
  float s0 = 0.f, s1 = 0.f, s2 = 0.f, s3 = 0.f;
#pragma unroll 4
  for (int r = 0; r < 64; ++r) {
    const float4 v = *reinterpret_cast<const float4*>(adj + (size_t)(row0 + r) * N_NODES + col0);
    s0 += v.x; s1 += v.y; s2 += v.z; s3 += v.w;
    bf16x4 o = { (bf16)v.x, (bf16)v.y, (bf16)v.z, (bf16)v.w };
    *reinterpret_cast<bf16x4*>(adjb + (size_t)(row0 + r) * N_NODES + col0) = o;
  }
  float4 ps = { s0, s1, s2, s3 };
  *reinterpret_cast<float4*>(partial + (size_t)blockIdx.y * N_NODES + col0) = ps;
}

// ---- kernel 2: d[j] = rsqrt(1 + colsum) ----
__global__ __launch_bounds__(256) void k_dvec(const float* __restrict__ partial,
                                              float* __restrict__ dv) {
  const int j = blockIdx.x * 256 + threadIdx.x;
  float s = 1.0f;  // +1 from the identity (self-loop)
#pragma unroll 8
  for (int p = 0; p < 128; ++p) s += partial[(size_t)p * N_NODES + j];
  dv[j] = rsqrtf(s);
}

// ---- kernel 3: Hst[k][j] = d[j]*H[j][k]  (transpose+scale, bf16; B^T layout for GEMM1) ----
__global__ __launch_bounds__(256) void k_hst(const float* __restrict__ H,
                                             const float* __restrict__ dv,
                                             bf16* __restrict__ Hst) {
  __shared__ float t[64][65];
  const int tid = threadIdx.x;
  const int j0 = blockIdx.x * 64;
  const int k0 = blockIdx.y * 64;
  const int rr = tid >> 4;         // 0..15
  const int cc = (tid & 15) * 4;   // 0..60
#pragma unroll
  for (int p = 0; p < 4; ++p) {
    const int r = p * 16 + rr;
    const float d = dv[j0 + r];
    float4 v = *reinterpret_cast<const float4*>(H + (size_t)(j0 + r) * N_IN + k0 + cc);
    t[r][cc + 0] = v.x * d; t[r][cc + 1] = v.y * d;
    t[r][cc + 2] = v.z * d; t[r][cc + 3] = v.w * d;
  }
  __syncthreads();
#pragma unroll
  for (int p = 0; p < 4; ++p) {
    const int kr = p * 16 + rr;
    bf16x4 o = { (bf16)t[cc + 0][kr], (bf16)t[cc + 1][kr],
                 (bf16)t[cc + 2][kr], (bf16)t[cc + 3][kr] };
    *reinterpret_cast<bf16x4*>(Hst + (size_t)(k0 + kr) * N_NODES + j0 + cc) = o;
  }
}

// ---- kernel 4: W fp32 -> bf16 (already B^T layout: [NOUT][NIN]) ----
__global__ __launch_bounds__(256) void k_wcvt(const float* __restrict__ W, bf16* __restrict__ Wb) {
  const int i = (blockIdx.x * 256 + threadIdx.x) * 4;
  float4 v = *reinterpret_cast<const float4*>(W + i);
  bf16x4 o = { (bf16)v.x, (bf16)v.y, (bf16)v.z, (bf16)v.w };
  *reinterpret_cast<bf16x4*>(Wb + i) = o;
}

// ================= 256x256-tile GEMM (gemm1): P[split] = A @ B^T ==================
// 8 waves (2Mx4N, wave-tile 128x64), BK=32, 4 LDS buffers (128 KB), depth-3
// prefetch with counted vmcnt (12/8/4, 0 only at drain), both-sides XOR swizzle
// (row stride 64B: colb = fk*16 ^ ((row>>1)&3)*16), setprio around MFMA cluster.
// Arithmetic intensity 128 FLOP/staged-byte (2x the 128^2 tile).
template<int KDIM, int NSPLIT>
__global__ __launch_bounds__(512, 2) void k_gemm256(
    const bf16* __restrict__ A, const bf16* __restrict__ B, float* __restrict__ P) {
  constexpr int KSEG = KDIM / NSPLIT;
  constexpr int NT = KSEG / 32;
  constexpr int NTN = 2;                       // N=512 -> 2 N-tiles of 256
  constexpr int NBLK = 32 * NTN * NSPLIT;
  __shared__ __attribute__((aligned(128))) char lds[4 * 32768];

  // XCD swizzle (NBLK%8==0 -> bijective); N-minor so the 2 N-tiles sharing an
  // A-panel are XCD-adjacent (A-panel L2 reuse).
  const int bid = blockIdx.x;
  const int logical = (bid & 7) * (NBLK / 8) + (bid >> 3);
  const int split = logical / (32 * NTN);
  const int rem = logical % (32 * NTN);
  const int bm0 = (rem >> 1) * 256;
  const int bn0 = (rem & 1) * 256;

  const int tid = threadIdx.x;
  const int lane = tid & 63;
  const int wid = tid >> 6;
  const int wr = wid >> 2;                     // 0..1  (M half)
  const int wc = wid & 3;                      // 0..3  (N quarter)

  // staging: linear LDS dest (global_load_lds), INVERSE-swizzled global source
  const int srow = tid >> 2;                   // 0..127
  const int scol = ((tid & 3) ^ ((srow >> 1) & 3)) << 3;   // elements
  const size_t a_src = (size_t)(bm0 + srow) * KDIM + (size_t)split * KSEG + scol;
  const size_t b_src = (size_t)(bn0 + srow) * KDIM + (size_t)split * KSEG + scol;

  // fragment reads (swizzled): byte = row*64 + (fk*16 ^ ((row>>1)&3)*16)
  const int frow = lane & 15;
  const int fk = lane >> 4;                    // 0..3
  const int colb = (fk << 4) ^ (((frow >> 1) & 3) << 4);
  const int a_base = (wr * 128 + frow) * 64 + colb;
  const int b_base = 16384 + (wc * 64 + frow) * 64 + colb;

  f32x4 acc[8][4] = {};

  auto stage = [&](int t) {
    char* lbase = lds + (t & 3) * 32768;
    const bf16* ag = A + a_src + (size_t)t * 32;
    const bf16* bg = B + b_src + (size_t)t * 32;
    gload16(ag,                        lbase +         tid * 16);
    gload16(ag + (size_t)128 * KDIM,   lbase +  8192 + tid * 16);
    gload16(bg,                        lbase + 16384 + tid * 16);
    gload16(bg + (size_t)128 * KDIM,   lbase + 24576 + tid * 16);
  };

  auto compute = [&](int t) {
    const char* lbase = lds + (t & 3) * 32768;
    bf16x8 av[8], bv[4];
#pragma unroll
    for (int m = 0; m < 8; ++m)
      av[m] = *reinterpret_cast<const bf16x8*>(lbase + a_base + m * 1024);
#pragma unroll
    for (int n = 0; n < 4; ++n)
      bv[n] = *reinterpret_cast<const bf16x8*>(lbase + b_base + n * 1024);
    __builtin_amdgcn_s_setprio(1);
#pragma unroll
    for (int m = 0; m < 8; ++m)
#pragma unroll
      for (int n = 0; n < 4; ++n)
        acc[m][n] = __builtin_amdgcn_mfma_f32_16x16x32_bf16(av[m], bv[n], acc[m][n], 0, 0, 0);
    __builtin_amdgcn_s_setprio(0);
  };

  stage(0); stage(1); stage(2);
#pragma unroll 1
  for (int t = 0; t < NT; ++t) {
    if (t + 3 < NT) stage(t + 3);
    const int ahead = NT - 1 - t;
    if (ahead >= 3)      WAITVM(12);   // 3 tiles x 4 loads in flight, tile t drained
    else if (ahead == 2) WAITVM(8);
    else if (ahead == 1) WAITVM(4);
    else                 WAITVM(0);
    __builtin_amdgcn_s_barrier();
    asm volatile("" ::: "memory");     // no LDS reads hoist above the barrier
    compute(t);
    asm volatile("" ::: "memory");
    __builtin_amdgcn_s_barrier();      // buffer t&3 rewritten at stage(t+4)
  }

  // epilogue: C/D layout col = lane&15, row = (lane>>4)*4 + j
#pragma unroll
  for (int m = 0; m < 8; ++m) {
#pragma unroll
    for (int j = 0; j < 4; ++j) {
      const int grow = bm0 + wr * 128 + m * 16 + (lane >> 4) * 4 + j;
      float* prow = P + (size_t)split * ((size_t)N_NODES * N_IN) + (size_t)grow * N_IN;
#pragma unroll
      for (int n = 0; n < 4; ++n) {
        const int gcol = bn0 + wc * 64 + n * 16 + (lane & 15);
        prow[gcol] = acc[m][n][j];
      }
    }
  }
}

// ---- 128x128-tile GEMM (gemm2): out = tanh(A @ B^T + bias), verified structure ----
template<int KDIM, int NSPLIT, int EPI>
__global__ __launch_bounds__(256, 2) void k_gemm(
    const bf16* __restrict__ A, const bf16* __restrict__ B,
    const float* __restrict__ bias, float* __restrict__ outf) {
  constexpr int KSEG = KDIM / NSPLIT;
  constexpr int NT = KSEG / 64;
  constexpr int NBLK = 256 * NSPLIT;
  __shared__ __attribute__((aligned(128))) char lds[2 * 32768];

  const int bid = blockIdx.x;
  const int logical = (bid & 7) * (NBLK / 8) + (bid >> 3);
  const int split = logical & (NSPLIT - 1);
  const int tile = logical / NSPLIT;
  const int bm0 = (tile >> 2) * 128;
  const int bn0 = (tile & 3) * 128;

  const int tid = threadIdx.x;
  const int wid = tid >> 6;
  const int lane = tid & 63;
  const int wr = wid & 1, wc = wid >> 1;

  const int srow = tid >> 3;
  const int scol = ((tid & 7) ^ (srow & 7)) << 3;
  const size_t a_src = (size_t)(bm0 + srow) * KDIM + (size_t)split * KSEG + scol;
  const size_t b_src = (size_t)(bn0 + srow) * KDIM + (size_t)split * KSEG + scol;

  const int frow = lane & 15;
  const int fk = lane >> 4;
  const int swz = (lane & 7) << 4;
  const int a_row_byte = (wr * 64 + frow) * 128;
  const int b_row_byte = 16384 + (wc * 64 + frow) * 128;

  f32x4 acc[4][4] = {};

  auto stage = [&](int t) {
    char* lbase = lds + (t & 1) * 32768;
    const bf16* ag = A + a_src + (size_t)t * 64;
    const bf16* bg = B + b_src + (size_t)t * 64;
#pragma unroll
    for (int ch = 0; ch < 4; ++ch) {
      gload16(ag + (size_t)(ch * 32) * KDIM, lbase + ch * 4096 + wid * 1024);
      gload16(bg + (size_t)(ch * 32) * KDIM, lbase + 16384 + ch * 4096 + wid * 1024);
    }
  };

  auto compute = [&](int t) {
    const char* lbase = lds + (t & 1) * 32768;
#pragma unroll
    for (int kk = 0; kk < 2; ++kk) {
      const int colb = (kk * 64 + fk * 16) ^ swz;
      bf16x8 av[4], bv[4];
#pragma unroll
      for (int m = 0; m < 4; ++m)
        av[m] = *reinterpret_cast<const bf16x8*>(lbase + a_row_byte + m * 2048 + colb);
#pragma unroll
      for (int n = 0; n < 4; ++n)
        bv[n] = *reinterpret_cast<const bf16x8*>(lbase + b_row_byte + n * 2048 + colb);
#pragma unroll
      for (int m = 0; m < 4; ++m)
#pragma unroll
        for (int n = 0; n < 4; ++n)
          acc[m][n] = __builtin_amdgcn_mfma_f32_16x16x32_bf16(av[m], bv[n], acc[m][n], 0, 0, 0);
    }
  };

  stage(0);
#pragma unroll 1
  for (int t = 0; t < NT - 1; ++t) {
    stage(t + 1);
    WAITVM(8);
    __builtin_amdgcn_s_barrier();
    asm volatile("" ::: "memory");
    compute(t);
    asm volatile("" ::: "memory");
    __builtin_amdgcn_s_barrier();
  }
  WAITVM(0);
  __builtin_amdgcn_s_barrier();
  compute(NT - 1);

#pragma unroll
  for (int m = 0; m < 4; ++m) {
#pragma unroll
    for (int j = 0; j < 4; ++j) {
      const int grow = bm0 + wr * 64 + m * 16 + (lane >> 4) * 4 + j;
      float* orow = outf + (size_t)grow * N_OUT;
#pragma unroll
      for (int n = 0; n < 4; ++n) {
        const int gcol = bn0 + wc * 64 + n * 16 + (lane & 15);
        float v = acc[m][n][j] + bias[gcol];
        v = fminf(fmaxf(v, -15.f), 15.f);
        const float e = __expf(2.f * v);
        orow[gcol] = (e - 1.f) / (e + 1.f);
      }
    }
  }
}

// ---- split-K reduce + GCN epilogue: Hm = d_i*(P0+P1+P2+P3) + d_i^2*H  (bf16) ----
__global__ __launch_bounds__(256) void k_red(const float* __restrict__ P,
                                             const float* __restrict__ H,
                                             const float* __restrict__ dv,
                                             bf16* __restrict__ Hm) {
  const int t = blockIdx.x * 256 + threadIdx.x;
  const int row = t >> 7;
  const int col = (t & 127) << 2;
  const size_t off = (size_t)row * N_IN + col;
  constexpr size_t S = (size_t)N_NODES * N_IN;
  const float d = dv[row];
  const float d2 = d * d;
  const float4 p0 = *reinterpret_cast<const float4*>(P + off);
  const float4 p1 = *reinterpret_cast<const float4*>(P + S + off);
  const float4 p2 = *reinterpret_cast<const float4*>(P + 2 * S + off);
  const float4 p3 = *reinterpret_cast<const float4*>(P + 3 * S + off);
  const float4 h  = *reinterpret_cast<const float4*>(H + off);
  bf16x4 o = { (bf16)(d * ((p0.x + p1.x) + (p2.x + p3.x)) + d2 * h.x),
               (bf16)(d * ((p0.y + p1.y) + (p2.y + p3.y)) + d2 * h.y),
               (bf16)(d * ((p0.z + p1.z) + (p2.z + p3.z)) + d2 * h.z),
               (bf16)(d * ((p0.w + p1.w) + (p2.w + p3.w)) + d2 * h.w) };
  *reinterpret_cast<bf16x4*>(Hm + off) = o;
}

extern "C" void kernel_launch(void* const* d_in, const int* in_sizes, int n_in,
                              void* d_out, int out_size, void* d_ws, size_t ws_size,
                              hipStream_t stream) {
  const float* H   = (const float*)d_in[0];
  const float* adj = (const float*)d_in[1];
  const float* W   = (const float*)d_in[2];
  const float* b   = (const float*)d_in[3];
  float* out = (float*)d_out;
  char* ws = (char*)d_ws;

  bf16*  adjb = (bf16*)(ws);                    // 8192*8192*2 = 134217728
  bf16*  Hst  = (bf16*)(ws + 134217728);        // 512*8192*2  = 8388608
  bf16*  Hm   = (bf16*)(ws + 142606336);        // 8192*512*2  = 8388608
  bf16*  Wb   = (bf16*)(ws + 150994944);        // 512*512*2   = 524288
  float* part = (float*)(ws + 151519232);       // 128*8192*4  = 4194304
  float* dv   = (float*)(ws + 155713536);       // 8192*4      = 32768
  float* P    = (float*)(ws + 155746304);       // 4*8192*512*4 = 67108864

  k_colsum_cvt<<<dim3(8, 128), 256, 0, stream>>>(adj, adjb, part);
  k_dvec<<<32, 256, 0, stream>>>(part, dv);
  k_hst<<<dim3(128, 8), 256, 0, stream>>>(H, dv, Hst);
  k_wcvt<<<256, 256, 0, stream>>>(W, Wb);
  // P[s] = adjb[:, s-quarter] @ Hst[s-quarter]^T   (split-K=4, f32 partials)
  k_gemm256<8192, 4><<<256, 512, 0, stream>>>(adjb, Hst, P);
  // Hm = d_i*(P0+P1+P2+P3) + d_i^2*H   (bf16)
  k_red<<<4096, 256, 0, stream>>>(P, H, dv, Hm);
  // out = tanh(Hm @ W^T + b)           (f32)
  k_gemm<512, 1, 1><<<256, 256, 0, stream>>>(Hm, Wb, b, out);
}